// Round 3
// baseline (9105.175 us; speedup 1.0000x reference)
//
#include <hip/hip_runtime.h>
#include <hip/hip_bf16.h>

// Problem constants
#define B_   4096
#define S_   64
#define D_   9
#define H_   128
#define HZ_  32
#define DT_  0.1f

// Workspace layout (float offsets, f32 region)
#define OFF_WET    0          // 16384  : W_e^T   (256 x 64)
#define OFF_VET    16384      // 4096   : V_e^T   (64 x 64)
#define OFF_WENCT  20480      // 70144  : W_enc^T (137 x 512)
#define OFF_BENC   90624      // 512
#define OFF_WDT    91136      // 32768  : (unused by new decoder, kept)
#define OFF_WDECT  123904     // 135680 : (unused by new decoder, kept)
#define OFF_BDEC   259584     // 512
#define OFF_WOUTT  260096     // 768    : W_out^T (256 x 3), cat=[d|ctx]
#define OFF_VDT    260864     // 16384  : V_d^T [i][k]
#define OFF_DECD   277248     // 524288 : final encoder h
#define OFF_DECC   801536     // 524288 : final encoder c
#define F32_TOTAL  1325824
#define PREP_N     277248

// bf16 (ushort) region after f32 region:
//   EH    : B*S*H            = 33554432
//   AET   : B*16*64*8        = 33554432   (k-packed attn_encoder^T)
//   WdTm  : 8ks*8nt*64*8     = 32768      (W_d in MFMA-B fragment order, K=[d;c])
//   WdecTm: 9ks*32nt*64*8    = 147456     (W_dec in MFMA-B order, K=[d;ctx;phys;0])

#define ENC_M 8
#define DEC_M 16

typedef __bf16 bf16x8 __attribute__((ext_vector_type(8)));
typedef float  f32x4  __attribute__((ext_vector_type(4)));

__device__ __forceinline__ float fast_tanh(float x) {
    float e = __expf(2.0f * x);
    return 1.0f - __fdividef(2.0f, e + 1.0f);
}
__device__ __forceinline__ float sigf(float x) {
    return __fdividef(1.0f, 1.0f + __expf(-x));
}
__device__ __forceinline__ float wred_sum(float v) {
    #pragma unroll
    for (int off = 32; off; off >>= 1) v += __shfl_xor(v, off, 64);
    return v;
}
__device__ __forceinline__ float bf_lo(unsigned int u) { return __uint_as_float(u << 16); }
__device__ __forceinline__ float bf_hi(unsigned int u) { return __uint_as_float(u & 0xffff0000u); }
__device__ __forceinline__ unsigned short f2bfu(float f) {
    __hip_bfloat16 b = __float2bfloat16(f);
    return *(unsigned short*)&b;
}
__device__ __forceinline__ unsigned int pack_bf(float lo, float hi) {
    return (unsigned int)f2bfu(lo) | ((unsigned int)f2bfu(hi) << 16);
}

// ---------------------------------------------------------------- prep (f32 tables)
__global__ void prep_kernel(const float* __restrict__ Wih_e, const float* __restrict__ Whh_e,
    const float* __restrict__ bih_e, const float* __restrict__ bhh_e,
    const float* __restrict__ W_e, const float* __restrict__ V_e,
    const float* __restrict__ W_d, const float* __restrict__ V_d,
    const float* __restrict__ Wih_d, const float* __restrict__ Whh_d,
    const float* __restrict__ bih_d, const float* __restrict__ bhh_d,
    const float* __restrict__ W_out, float* __restrict__ ws) {
  for (int idx = blockIdx.x * blockDim.x + threadIdx.x; idx < PREP_N;
       idx += gridDim.x * blockDim.x) {
    int i = idx;
    if (i < 16384) { int k = i >> 6, s = i & 63; ws[OFF_WET + i] = W_e[s * 256 + k]; continue; }
    i -= 16384;
    if (i < 4096) { int s = i >> 6, t = i & 63; ws[OFF_VET + i] = V_e[t * 64 + s]; continue; }
    i -= 4096;
    if (i < 70144) {
      int k = i / 512, g = i & 511;
      ws[OFF_WENCT + i] = (k < 128) ? Whh_e[g * 128 + k] : Wih_e[g * 9 + (k - 128)];
      continue;
    }
    i -= 70144;
    if (i < 512) { ws[OFF_BENC + i] = bih_e[i] + bhh_e[i]; continue; }
    i -= 512;
    if (i < 32768) { int k = i >> 7, j = i & 127; ws[OFF_WDT + i] = W_d[j * 256 + k]; continue; }
    i -= 32768;
    if (i < 135680) {
      int k = i / 512, g = i & 511; float v;
      if (k < 128)      v = Whh_d[g * 128 + k];
      else if (k < 256) v = Wih_d[g * 137 + 9 + (k - 128)];
      else              v = Wih_d[g * 137 + (k - 256)];
      ws[OFF_WDECT + i] = v; continue;
    }
    i -= 135680;
    if (i < 512) { ws[OFF_BDEC + i] = bih_d[i] + bhh_d[i]; continue; }
    i -= 512;
    if (i < 768) { int k = i / 3, j = i % 3; ws[OFF_WOUTT + i] = W_out[j * 256 + k]; continue; }
    i -= 768;
    { int ii = i >> 7, j = i & 127; ws[OFF_VDT + i] = V_d[j * 128 + ii]; }
  }
}

// ---------------------------------------------------------------- prep (MFMA B-fragment bf16 weights)
// WdTm[ks(8)][nt(8)][lane(64)][8]  : k=ks*32+(l>>4)*8+j (K=[d;c]), n=nt*16+(l&15); val=W_d[n][k]
// WdecTm[ks(9)][nt(32)][lane][8]   : k over [d128|ctx128|phys9|0..], g=nt*16+(l&15)
__global__ void prep_mfma_kernel(const float* __restrict__ W_d,
    const float* __restrict__ Wih_d, const float* __restrict__ Whh_d,
    unsigned short* __restrict__ WdTm, unsigned short* __restrict__ WdecTm) {
  int idx = blockIdx.x * blockDim.x + threadIdx.x;
  if (idx < 32768) {
    int j = idx & 7, l = (idx >> 3) & 63, t = idx >> 9;
    int nt = t & 7, ks = t >> 3;
    int k = ks * 32 + (l >> 4) * 8 + j;
    int n = nt * 16 + (l & 15);
    WdTm[idx] = f2bfu(W_d[n * 256 + k]);
    return;
  }
  int i2 = idx - 32768;
  if (i2 < 147456) {
    int j = i2 & 7, l = (i2 >> 3) & 63, t = i2 >> 9;
    int nt = t & 31, ks = t >> 5;
    int k = ks * 32 + (l >> 4) * 8 + j;
    int g = nt * 16 + (l & 15);
    float v;
    if (k < 128)      v = Whh_d[g * 128 + k];
    else if (k < 256) v = Wih_d[g * 137 + 9 + (k - 128)];
    else if (k < 265) v = Wih_d[g * 137 + (k - 256)];
    else              v = 0.f;
    WdecTm[i2] = f2bfu(v);
  }
}

// ---------------------------------------------------------------- encoder (R1 form, ENC_M=8)
__global__ __launch_bounds__(256, 2) void encoder_kernel(
    const float* __restrict__ x_in, const float* __restrict__ ws,
    const float* __restrict__ v_e_g, __hip_bfloat16* __restrict__ EH,
    float* __restrict__ decd, float* __restrict__ decc) {
  __shared__ float hc[ENC_M][272];
  __shared__ float xb[ENC_M][576];
  __shared__ float ai[ENC_M][576];
  __shared__ float ah[ENC_M][64];
  __shared__ float gl[ENC_M][512];
  __shared__ float ve[64];

  const int tid = threadIdx.x;
  const int b0 = blockIdx.x * ENC_M;
  const int lane = tid & 63, wv = tid >> 6;

  for (int i = tid; i < ENC_M * 576; i += 256) {
    int m = i / 576, r = i % 576;
    xb[m][r] = x_in[(size_t)(b0 + m) * 576 + r];
  }
  if (tid < 64) ve[tid] = v_e_g[tid];
  for (int i = tid; i < ENC_M * 256; i += 256) { int m = i >> 8, r = i & 255; hc[m][r] = 0.f; }
  __syncthreads();

  const float* __restrict__ VeT = ws + OFF_VET;
  for (int i = tid; i < ENC_M * 576; i += 256) {
    int t = i & 63, dd = (i >> 6) % 9, m = i / 576;
    float acc = 0.f;
    for (int s = 0; s < 64; ++s) acc += xb[m][s * 9 + dd] * VeT[s * 64 + t];
    ai[m][dd * 64 + t] = acc;
  }
  __syncthreads();

  const float* __restrict__ WeT   = ws + OFF_WET;
  const float* __restrict__ WencT = ws + OFF_WENCT;
  const float* __restrict__ benc  = ws + OFF_BENC;

  for (int t = 0; t < S_; ++t) {
    {
      const int s = lane, m0 = wv, m1 = wv + 4;
      float a0 = 0.f, a1 = 0.f;
      for (int k = 0; k < 256; k += 4) {
        float w0 = WeT[(k + 0) * 64 + s], w1 = WeT[(k + 1) * 64 + s];
        float w2 = WeT[(k + 2) * 64 + s], w3 = WeT[(k + 3) * 64 + s];
        const float4 h0 = *(const float4*)&hc[m0][k];
        const float4 h1 = *(const float4*)&hc[m1][k];
        a0 += w0 * h0.x + w1 * h0.y + w2 * h0.z + w3 * h0.w;
        a1 += w0 * h1.x + w1 * h1.y + w2 * h1.z + w3 * h1.w;
      }
      ah[m0][s] = a0; ah[m1][s] = a1;
    }
    __syncthreads();
    #pragma unroll
    for (int half = 0; half < 2; ++half) {
      const int mi = wv + half * 4;
      float e_reg = -1e30f;
      for (int dd = 0; dd < 9; ++dd) {
        float a  = ah[mi][lane] + ai[mi][dd * 64 + lane];
        float tv = fast_tanh(a) * ve[lane];
        float e_dd = wred_sum(tv);
        if (lane == dd) e_reg = e_dd;
      }
      float mval = e_reg;
      #pragma unroll
      for (int off = 8; off; off >>= 1) mval = fmaxf(mval, __shfl_xor(mval, off, 64));
      float ex = (lane < 9) ? __expf(e_reg - mval) : 0.f;
      float ssum = ex;
      #pragma unroll
      for (int off = 8; off; off >>= 1) ssum += __shfl_xor(ssum, off, 64);
      if (lane < 9) hc[mi][256 + lane] = __fdividef(ex, ssum) * xb[mi][t * 9 + lane];
    }
    __syncthreads();
    {
      const int g0 = tid, g1 = tid + 256;
      float acc0[ENC_M], acc1[ENC_M];
      const float bb0 = benc[g0], bb1 = benc[g1];
      #pragma unroll
      for (int m = 0; m < ENC_M; ++m) { acc0[m] = bb0; acc1[m] = bb1; }
      for (int k = 0; k < 128; k += 4) {
        float w00 = WencT[(k + 0) * 512 + g0], w01 = WencT[(k + 0) * 512 + g1];
        float w10 = WencT[(k + 1) * 512 + g0], w11 = WencT[(k + 1) * 512 + g1];
        float w20 = WencT[(k + 2) * 512 + g0], w21 = WencT[(k + 2) * 512 + g1];
        float w30 = WencT[(k + 3) * 512 + g0], w31 = WencT[(k + 3) * 512 + g1];
        #pragma unroll
        for (int m = 0; m < ENC_M; ++m) {
          const float4 hv = *(const float4*)&hc[m][k];
          acc0[m] += w00 * hv.x + w10 * hv.y + w20 * hv.z + w30 * hv.w;
          acc1[m] += w01 * hv.x + w11 * hv.y + w21 * hv.z + w31 * hv.w;
        }
      }
      #pragma unroll
      for (int k = 0; k < 9; ++k) {
        float w0 = WencT[(128 + k) * 512 + g0], w1 = WencT[(128 + k) * 512 + g1];
        #pragma unroll
        for (int m = 0; m < ENC_M; ++m) {
          float xv = hc[m][256 + k];
          acc0[m] += w0 * xv; acc1[m] += w1 * xv;
        }
      }
      #pragma unroll
      for (int m = 0; m < ENC_M; ++m) { gl[m][g0] = acc0[m]; gl[m][g1] = acc1[m]; }
    }
    __syncthreads();
    #pragma unroll
    for (int q = 0; q < 4; ++q) {
      int flat = tid + q * 256;
      int m = flat >> 7, i = flat & 127;
      float gi = gl[m][i], gf = gl[m][128 + i], gg = gl[m][256 + i], go = gl[m][384 + i];
      float co = hc[m][128 + i];
      float cn = sigf(gf) * co + sigf(gi) * fast_tanh(gg);
      float hn = sigf(go) * fast_tanh(cn);
      hc[m][i] = hn; hc[m][128 + i] = cn;
      EH[((size_t)(b0 + m) * S_ + t) * H_ + i] = __float2bfloat16(hn);
    }
    __syncthreads();
  }
  #pragma unroll
  for (int q = 0; q < 4; ++q) {
    int flat = tid + q * 256;
    int m = flat >> 7, i = flat & 127;
    decd[(size_t)(b0 + m) * H_ + i] = hc[m][i];
    decc[(size_t)(b0 + m) * H_ + i] = hc[m][128 + i];
  }
}

// ---------------------------------------------------------------- attn_encoder^T (k-packed)
__global__ __launch_bounds__(256, 4) void attnenc_t_kernel(const float* __restrict__ ws,
    const __hip_bfloat16* __restrict__ EH, unsigned short* __restrict__ AET) {
  __shared__ float EHsT[128 * 65];
  const int tid = threadIdx.x;
  const int b = blockIdx.x;
  const int s = tid & 63, kq = tid >> 6;

  for (int flat = tid; flat < 8192; flat += 256) {
    int ss = flat >> 7, ii = flat & 127;
    EHsT[ii * 65 + ss] = __bfloat162float(EH[(size_t)b * 8192 + flat]);
  }
  __syncthreads();

  const float* __restrict__ VdT = ws + OFF_VDT;
  float4 acc[8];
  #pragma unroll
  for (int g = 0; g < 8; ++g) acc[g] = make_float4(0.f, 0.f, 0.f, 0.f);
  for (int i = 0; i < 128; ++i) {
    float e = EHsT[i * 65 + s];
    const float4* w4 = (const float4*)(VdT + i * 128 + kq * 32);
    #pragma unroll
    for (int g = 0; g < 8; ++g) {
      float4 w = w4[g];
      acc[g].x += e * w.x; acc[g].y += e * w.y; acc[g].z += e * w.z; acc[g].w += e * w.w;
    }
  }
  unsigned short* outp = AET + (size_t)b * 8192;
  #pragma unroll
  for (int g = 0; g < 4; ++g) {
    float4 a0 = acc[2 * g], a1 = acc[2 * g + 1];
    uint4 pk;
    pk.x = pack_bf(a0.x, a0.y); pk.y = pack_bf(a0.z, a0.w);
    pk.z = pack_bf(a1.x, a1.y); pk.w = pack_bf(a1.z, a1.w);
    *(uint4*)(outp + (size_t)(kq * 4 + g) * 512 + s * 8) = pk;
  }
}

// ---------------------------------------------------------------- decoder (MFMA, DEC_M=16, 512 thr)
__global__ __launch_bounds__(512, 2) void decoder_kernel(
    const float* __restrict__ x_in, const float* __restrict__ ws,
    const __hip_bfloat16* __restrict__ EH, const unsigned short* __restrict__ AET,
    const unsigned short* __restrict__ WdTm, const unsigned short* __restrict__ WdecTm,
    const float* __restrict__ v_d_g, const float* __restrict__ b_out_g,
    const float* __restrict__ smean_g, const float* __restrict__ sstd_g,
    const float* __restrict__ pmean_g, float* __restrict__ out) {
  // LDS
  __shared__ unsigned short dcA[16 * 264];   // bf16 [d(0..127)|c(128..255)] row stride 264
  __shared__ unsigned short gA[16 * 296];    // bf16 [d|ctx|phys|0pad] row stride 296 (K=288 used)
  __shared__ float ad_s[16 * 128];
  __shared__ float beta_s[16 * 64];
  __shared__ float gl_s[16 * 512];
  __shared__ float cst[16 * 128];            // c state f32
  __shared__ float wout[768];
  __shared__ float vd[128];
  __shared__ float bds[512];
  __shared__ float partials[384];
  __shared__ float pvs[16][12];
  __shared__ float cons[12];

  const int tid = threadIdx.x;
  const int b0 = blockIdx.x * DEC_M;
  const int l = tid & 63, w = tid >> 6;        // 8 waves

  const float* __restrict__ decd = ws + OFF_DECD;
  const float* __restrict__ decc = ws + OFF_DECC;

  // ---- init
  for (int flat = tid; flat < 16 * 128; flat += 512) {
    int m = flat >> 7, i = flat & 127;
    float dv = decd[(size_t)(b0 + m) * H_ + i];
    float cv = decc[(size_t)(b0 + m) * H_ + i];
    dcA[m * 264 + i]       = f2bfu(dv);
    dcA[m * 264 + 128 + i] = f2bfu(cv);
    gA[m * 296 + i]        = f2bfu(dv);
    cst[flat] = cv;
  }
  for (int flat = tid; flat < 16 * 40; flat += 512) {  // zero gA[256..295]
    int m = flat / 40, r = flat % 40;
    gA[m * 296 + 256 + r] = 0;
  }
  for (int i = tid; i < 768; i += 512) wout[i] = ws[OFF_WOUTT + i];
  if (tid < 128) vd[tid] = v_d_g[tid];
  if (tid < 512) bds[tid] = ws[OFF_BDEC + tid];
  if (tid < 3) { cons[tid] = smean_g[tid]; cons[3 + tid] = sstd_g[tid]; cons[6 + tid] = pmean_g[tid]; }
  __syncthreads();
  if (tid < 48) {
    int m = tid / 3, jj = tid % 3;
    const float* xi = x_in + (size_t)(b0 + m) * 576;
    float v  = xi[63 * 9 + 3 + jj] * cons[3 + jj] + cons[jj];
    float pv = xi[62 * 9 + 3 + jj] * cons[3 + jj] + cons[jj];
    pvs[m][jj]     = xi[63 * 9 + jj] + cons[6 + jj];
    pvs[m][3 + jj] = v;
    pvs[m][6 + jj] = (v - pv) / DT_;
  }
  __syncthreads();

  const int quad = l >> 4, l15 = l & 15;

  for (int hz = 0; hz < HZ_; ++hz) {
    // ---- A: ad = [d;c] @ W_d^T via MFMA. wave w handles n-tile nt=w.
    {
      f32x4 acc = {0.f, 0.f, 0.f, 0.f};
      #pragma unroll
      for (int ks = 0; ks < 8; ++ks) {
        uint4 au = *(const uint4*)&dcA[l15 * 264 + ks * 32 + quad * 8];
        uint4 bu = *(const uint4*)(WdTm + (size_t)((ks * 8 + w) * 64 + l) * 8);
        acc = __builtin_amdgcn_mfma_f32_16x16x32_bf16(
            __builtin_bit_cast(bf16x8, au), __builtin_bit_cast(bf16x8, bu), acc, 0, 0, 0);
      }
      int n = w * 16 + l15;
      #pragma unroll
      for (int r = 0; r < 4; ++r) {
        int m = quad * 4 + r;
        ad_s[m * 128 + n] = acc[r];
      }
    }
    __syncthreads();
    // ---- B: scores + softmax, lane = s. Wave w: batches 2w, 2w+1.
    #pragma unroll
    for (int u = 0; u < 2; ++u) {
      const int mi = 2 * w + u;
      const unsigned short* aet = AET + (size_t)(b0 + mi) * 8192;
      const float4* adp = (const float4*)&ad_s[mi * 128];
      const float4* vdp = (const float4*)&vd[0];
      float e_acc = 0.f;
      #pragma unroll
      for (int kb = 0; kb < 16; ++kb) {
        uint4 av = *(const uint4*)(aet + (size_t)kb * 512 + l * 8);
        float4 a0 = adp[kb * 2], a1 = adp[kb * 2 + 1];
        float4 v0 = vdp[kb * 2], v1 = vdp[kb * 2 + 1];
        e_acc += fast_tanh(a0.x + bf_lo(av.x)) * v0.x;
        e_acc += fast_tanh(a0.y + bf_hi(av.x)) * v0.y;
        e_acc += fast_tanh(a0.z + bf_lo(av.y)) * v0.z;
        e_acc += fast_tanh(a0.w + bf_hi(av.y)) * v0.w;
        e_acc += fast_tanh(a1.x + bf_lo(av.z)) * v1.x;
        e_acc += fast_tanh(a1.y + bf_hi(av.z)) * v1.y;
        e_acc += fast_tanh(a1.z + bf_lo(av.w)) * v1.z;
        e_acc += fast_tanh(a1.w + bf_hi(av.w)) * v1.w;
      }
      float mx = e_acc;
      #pragma unroll
      for (int off = 32; off; off >>= 1) mx = fmaxf(mx, __shfl_xor(mx, off, 64));
      float ex = __expf(e_acc - mx);
      float ss = ex;
      #pragma unroll
      for (int off = 32; off; off >>= 1) ss += __shfl_xor(ss, off, 64);
      beta_s[mi * 64 + l] = __fdividef(ex, ss);
    }
    __syncthreads();
    // ---- C: context (vectorized EH stream). Wave w: batches 2w, 2w+1.
    #pragma unroll
    for (int u = 0; u < 2; ++u) {
      const int mi = 2 * w + u;
      const int sg = quad, c16 = l15;
      const __hip_bfloat16* base = EH + (size_t)(b0 + mi) * 8192;
      float a[8];
      #pragma unroll
      for (int r = 0; r < 8; ++r) a[r] = 0.f;
      #pragma unroll
      for (int it = 0; it < 16; ++it) {
        int s = it * 4 + sg;
        uint4 ev = *(const uint4*)(base + (size_t)s * 128 + c16 * 8);
        float bt = beta_s[mi * 64 + s];
        a[0] += bt * bf_lo(ev.x); a[1] += bt * bf_hi(ev.x);
        a[2] += bt * bf_lo(ev.y); a[3] += bt * bf_hi(ev.y);
        a[4] += bt * bf_lo(ev.z); a[5] += bt * bf_hi(ev.z);
        a[6] += bt * bf_lo(ev.w); a[7] += bt * bf_hi(ev.w);
      }
      #pragma unroll
      for (int r = 0; r < 8; ++r) {
        a[r] += __shfl_xor(a[r], 16, 64);
        a[r] += __shfl_xor(a[r], 32, 64);
      }
      if (sg == 0) {
        uint4 pk;
        pk.x = pack_bf(a[0], a[1]); pk.y = pack_bf(a[2], a[3]);
        pk.z = pack_bf(a[4], a[5]); pk.w = pack_bf(a[6], a[7]);
        *(uint4*)&gA[mi * 296 + 128 + c16 * 8] = pk;
      }
    }
    if (tid < 48) {   // phys -> gA[256..264] (bf16)
      int m = tid / 3, jj = tid % 3;
      gA[m * 296 + 256 + jj]     = f2bfu(pvs[m][jj] - cons[6 + jj]);
      gA[m * 296 + 256 + 3 + jj] = f2bfu((pvs[m][3 + jj] - cons[jj]) / cons[3 + jj]);
      gA[m * 296 + 256 + 6 + jj] = f2bfu(pvs[m][6 + jj] / cons[3 + jj]);
    }
    __syncthreads();
    // ---- D: gates = [d;ctx;phys] @ W_dec^T via MFMA. Wave w: nt = 4w..4w+3.
    {
      uint4 af[9];
      #pragma unroll
      for (int ks = 0; ks < 9; ++ks)
        af[ks] = *(const uint4*)&gA[l15 * 296 + ks * 32 + quad * 8];
      #pragma unroll
      for (int q = 0; q < 4; ++q) {
        const int nt = w * 4 + q;
        f32x4 acc = {0.f, 0.f, 0.f, 0.f};
        #pragma unroll
        for (int ks = 0; ks < 9; ++ks) {
          uint4 bu = *(const uint4*)(WdecTm + (size_t)((ks * 32 + nt) * 64 + l) * 8);
          acc = __builtin_amdgcn_mfma_f32_16x16x32_bf16(
              __builtin_bit_cast(bf16x8, af[ks]), __builtin_bit_cast(bf16x8, bu), acc, 0, 0, 0);
        }
        int g = nt * 16 + l15;
        float bb = bds[g];
        #pragma unroll
        for (int r = 0; r < 4; ++r) {
          int m = quad * 4 + r;
          gl_s[m * 512 + g] = acc[r] + bb;
        }
      }
    }
    __syncthreads();
    // ---- E: LSTM cell update
    #pragma unroll
    for (int q = 0; q < 4; ++q) {
      int flat = tid + q * 512;
      int m = flat >> 7, i = flat & 127;
      float gi = gl_s[m * 512 + i], gf = gl_s[m * 512 + 128 + i];
      float gg = gl_s[m * 512 + 256 + i], go = gl_s[m * 512 + 384 + i];
      float co = cst[flat];
      float cn = sigf(gf) * co + sigf(gi) * fast_tanh(gg);
      float hn = sigf(go) * fast_tanh(cn);
      cst[flat] = cn;
      unsigned short hb = f2bfu(hn);
      dcA[m * 264 + i]       = hb;
      dcA[m * 264 + 128 + i] = f2bfu(cn);
      gA[m * 296 + i]        = hb;
    }
    __syncthreads();
    // ---- F: pred_acc partial dots over [d|ctx] (bf16 from gA)
    if (tid < 384) {
      int m = tid / 24, jj = (tid % 24) / 8, part = tid % 8;
      int k0 = part * 32;
      float acc = 0.f;
      for (int k = k0; k < k0 + 32; ++k) {
        __hip_bfloat16 hv = *(__hip_bfloat16*)&gA[m * 296 + k];
        acc += __bfloat162float(hv) * wout[k * 3 + jj];
      }
      partials[tid] = acc;
    }
    __syncthreads();
    // ---- G: Verlet + output
    if (tid < 48) {
      int m = tid / 3, jj = tid % 3;
      float s = b_out_g[jj];
      #pragma unroll
      for (int p = 0; p < 8; ++p) s += partials[m * 24 + jj * 8 + p];
      float pacc = s * cons[3 + jj];
      float pos = pvs[m][jj], vel = pvs[m][3 + jj], acc = pvs[m][6 + jj];
      float ppred = pos + vel * DT_ + 0.5f * acc * DT_ * DT_;
      float vnew  = vel + 0.5f * (acc + pacc) * DT_;
      size_t ob = ((size_t)(b0 + m) * HZ_ + hz) * 9;
      out[ob + jj] = ppred; out[ob + 3 + jj] = vnew; out[ob + 6 + jj] = pacc;
      pvs[m][jj] = ppred; pvs[m][3 + jj] = vnew; pvs[m][6 + jj] = pacc;
    }
    __syncthreads();
  }
}

// ---------------------------------------------------------------- launch
extern "C" void kernel_launch(void* const* d_in, const int* in_sizes, int n_in,
                              void* d_out, int out_size, void* d_ws, size_t ws_size,
                              hipStream_t stream) {
  (void)in_sizes; (void)n_in; (void)out_size; (void)ws_size;
  const float* x      = (const float*)d_in[0];
  const float* Wih_e  = (const float*)d_in[1];
  const float* Whh_e  = (const float*)d_in[2];
  const float* bih_e  = (const float*)d_in[3];
  const float* bhh_e  = (const float*)d_in[4];
  const float* W_e    = (const float*)d_in[5];
  const float* V_e    = (const float*)d_in[6];
  const float* v_e    = (const float*)d_in[7];
  const float* W_d    = (const float*)d_in[8];
  const float* V_d    = (const float*)d_in[9];
  const float* v_d    = (const float*)d_in[10];
  const float* Wih_d  = (const float*)d_in[11];
  const float* Whh_d  = (const float*)d_in[12];
  const float* bih_d  = (const float*)d_in[13];
  const float* bhh_d  = (const float*)d_in[14];
  const float* W_out  = (const float*)d_in[15];
  const float* b_out  = (const float*)d_in[16];
  const float* smean  = (const float*)d_in[17];
  const float* sstd   = (const float*)d_in[18];
  const float* pmean  = (const float*)d_in[19];

  float* ws = (float*)d_ws;
  __hip_bfloat16* EH  = (__hip_bfloat16*)(ws + F32_TOTAL);
  unsigned short* AET = (unsigned short*)(EH + (size_t)B_ * S_ * H_);
  unsigned short* WdTm   = AET + (size_t)B_ * S_ * H_;
  unsigned short* WdecTm = WdTm + 32768;
  float* out = (float*)d_out;

  prep_kernel<<<(PREP_N + 255) / 256, 256, 0, stream>>>(
      Wih_e, Whh_e, bih_e, bhh_e, W_e, V_e, W_d, V_d,
      Wih_d, Whh_d, bih_d, bhh_d, W_out, ws);
  prep_mfma_kernel<<<(32768 + 147456 + 255) / 256, 256, 0, stream>>>(
      W_d, Wih_d, Whh_d, WdTm, WdecTm);
  encoder_kernel<<<B_ / ENC_M, 256, 0, stream>>>(
      x, ws, v_e, EH, ws + OFF_DECD, ws + OFF_DECC);
  attnenc_t_kernel<<<B_, 256, 0, stream>>>(ws, EH, AET);
  decoder_kernel<<<B_ / DEC_M, 512, 0, stream>>>(
      x, ws, EH, AET, WdTm, WdecTm, v_d, b_out, smean, sstd, pmean, out);
}